// Round 2
// baseline (6512.750 us; speedup 1.0000x reference)
//
#include <hip/hip_runtime.h>

typedef unsigned short u16;
typedef unsigned int u32;

#define L 512
#define BB 512
#define NROWS (L*BB)            // 262144
#define CH (NROWS*64)           // 16777216 elements per output chunk

// f32 weight offsets inside d_ws
enum {
  O_PUW1 = 0,
  O_PUB1 = 1024,
  O_PUW2 = 1088,
  O_PUB2 = 5184,
  O_PXW1 = 5248,
  O_PXB1 = 6272,
  O_PXW2 = 6336,
  O_PXB2 = 10432,
  O_WIH  = 10496,
  O_RNB  = 14592,   // bih + bhh
  O_WHH  = 14656,
  O_AW1  = 18752,   // 64x128
  O_AB1  = 26944,
  O_AW2  = 27008,
  O_AB2  = 31104,
  O_POF1 = 31168,   // 128x128
  O_POF1B= 47552,
  O_POF2 = 47680,
  O_POF2B= 64064,
  O_POMU = 64192,   // 64x128
  O_POMUB= 72384,
  O_POLS = 72448,
  O_POLSB= 80640,
  O_PRF1 = 80704,
  O_PRF1B= 97088,
  O_PRF2 = 97216,
  O_PRF2B= 113600,
  O_PRMU = 113728,
  O_PRMUB= 121920,
  O_FLAG = 121984,  // u32 dtype flag: 1 = bf16 device data, 2 = f32 device data
  O_END  = 121985
};

__device__ __forceinline__ float b2f(u16 x){ return __uint_as_float(((u32)x)<<16); }
__device__ __forceinline__ u16 f2b(float f){
  u32 u = __float_as_uint(f);
  u32 r = (u + 0x7fffu + ((u>>16)&1u)) >> 16;
  return (u16)r;
}

#if __has_builtin(__builtin_amdgcn_exp2f)
#define EXP2(x) __builtin_amdgcn_exp2f(x)
#else
#define EXP2(x) exp2f(x)
#endif
#if __has_builtin(__builtin_amdgcn_rcpf)
#define RCP(x) __builtin_amdgcn_rcpf(x)
#else
#define RCP(x) (1.0f/(x))
#endif

__device__ __forceinline__ float tanhf_fast(float x){
  float e = EXP2(x * 2.8853900817779268f);
  return 1.0f - 2.0f * RCP(e + 1.0f);
}
__device__ __forceinline__ float sigm_fast(float x){
  float e = EXP2(-1.4426950408889634f * x);
  return RCP(1.0f + e);
}

// plain-C packed bf16 pair dot-accumulate (no exotic instructions this round)
__device__ __forceinline__ float dot2c(u32 w, u32 a, float c){
  c = fmaf(b2f((u16)(w & 0xffffu)), b2f((u16)(a & 0xffffu)), c);
  return fmaf(b2f((u16)(w >> 16)), b2f((u16)(a >> 16)), c);
}

// ---- MODE-generic load/store helpers (MODE 0: bf16 device data, 1: f32) ----
template<int MODE>
__device__ __forceinline__ float ldOne(const void* p, size_t i){
  if constexpr (MODE) return ((const float*)p)[i];
  else return b2f(((const u16*)p)[i]);
}
template<int MODE>
__device__ __forceinline__ void stOne(void* p, size_t i, float v){
  if constexpr (MODE) ((float*)p)[i] = v;
  else ((u16*)p)[i] = f2b(v);
}
// load elements (base+2w, base+2w+1) packed as bf16x2 word
template<int MODE>
__device__ __forceinline__ u32 ldpk(const void* p, size_t base, int w){
  if constexpr (MODE){
    float2 v = ((const float2*)((const float*)p + base))[w];
    return (u32)f2b(v.x) | ((u32)f2b(v.y) << 16);
  } else {
    return ((const u32*)((const u16*)p + base))[w];
  }
}
template<int MODE>
__device__ __forceinline__ float wld(const void* p, int i){
  if constexpr (MODE) return ((const float*)p)[i];
  else return b2f(((const u16*)p)[i]);
}
template<int MODE>
__device__ __forceinline__ void* chunkp(void* out, int j){
  return (void*)((char*)out + (size_t)j * (size_t)CH * (MODE ? 4 : 2));
}
__device__ __forceinline__ bool live(const float* W, int tag){
  return ((const u32*)W)[O_FLAG] == (u32)tag;
}

// -------------------- probe: classify device dtype --------------------
// bf16-packed data: low u16 of each u32 is a bf16 of ~N(0,1) -> exponent field in [110,134] ~always.
// f32 data: low u16 is mantissa noise -> exponent field uniform -> ~10% in range.
__global__ void kprobe(const u32* __restrict__ ext, u32* __restrict__ flagp){
  if (threadIdx.x == 0 && blockIdx.x == 0){
    int cnt = 0;
    for (int i = 0; i < 1024; ++i){
      u32 e = (ext[i] >> 7) & 0xFFu;
      cnt += (e >= 110u && e <= 134u) ? 1 : 0;
    }
    flagp[0] = (cnt > 512) ? 1u : 2u;
  }
}

// -------------------- K0: weights -> f32 in ws --------------------
template<int MODE>
__global__ void k0_convert(
  const void* pu_w1, const void* pu_b1, const void* pu_w2, const void* pu_b2,
  const void* px_w1, const void* px_b1, const void* px_w2, const void* px_b2,
  const void* rnn_wih, const void* rnn_whh, const void* rnn_bih, const void* rnn_bhh,
  const void* a_w1, const void* a_b1, const void* a_w2, const void* a_b2,
  const void* po_f1, const void* po_f1b, const void* po_f2, const void* po_f2b,
  const void* po_mu, const void* po_mub, const void* po_ls, const void* po_lsb,
  const void* pr_f1, const void* pr_f1b, const void* pr_f2, const void* pr_f2b,
  const void* pr_mu, const void* pr_mub,
  float* W)
{
  if (!live(W, MODE ? 2 : 1)) return;
  const int g = blockIdx.x*blockDim.x + threadIdx.x;
  const int gs = gridDim.x*blockDim.x;
#define CVT(off, src, n) for (int i=g;i<(n);i+=gs) W[(off)+i] = wld<MODE>(src,i);
  CVT(O_PUW1, pu_w1, 1024)  CVT(O_PUB1, pu_b1, 64)
  CVT(O_PUW2, pu_w2, 4096)  CVT(O_PUB2, pu_b2, 64)
  CVT(O_PXW1, px_w1, 1024)  CVT(O_PXB1, px_b1, 64)
  CVT(O_PXW2, px_w2, 4096)  CVT(O_PXB2, px_b2, 64)
  CVT(O_WIH,  rnn_wih, 4096)
  CVT(O_WHH,  rnn_whh, 4096)
  CVT(O_AW1,  a_w1, 8192)   CVT(O_AB1, a_b1, 64)
  CVT(O_AW2,  a_w2, 4096)   CVT(O_AB2, a_b2, 64)
  CVT(O_POF1, po_f1, 16384) CVT(O_POF1B, po_f1b, 128)
  CVT(O_POF2, po_f2, 16384) CVT(O_POF2B, po_f2b, 128)
  CVT(O_POMU, po_mu, 8192)  CVT(O_POMUB, po_mub, 64)
  CVT(O_POLS, po_ls, 8192)  CVT(O_POLSB, po_lsb, 64)
  CVT(O_PRF1, pr_f1, 16384) CVT(O_PRF1B, pr_f1b, 128)
  CVT(O_PRF2, pr_f2, 16384) CVT(O_PRF2B, pr_f2b, 128)
  CVT(O_PRMU, pr_mu, 8192)  CVT(O_PRMUB, pr_mub, 64)
#undef CVT
  for (int i=g;i<64;i+=gs) W[O_RNB+i] = wld<MODE>(rnn_bih,i) + wld<MODE>(rnn_bhh,i);
}

// -------------------- K1: parallel prep (thread-per-row) --------------------
// rnn_in = u_emb@Wih^T + bih + bhh  -> chunk1 (scratch)
// ax     = a_w1[:,64:]@x_emb + a_b1 -> chunk2 (scratch)
template<int MODE>
__global__ __launch_bounds__(256) void k1_prep(
  const void* __restrict__ ext, const void* __restrict__ obs,
  const float* __restrict__ W, void* __restrict__ outb)
{
  if (!live(W, MODE ? 2 : 1)) return;
  void* rnn_in = chunkp<MODE>(outb, 1);
  void* ax_out = chunkp<MODE>(outb, 2);

  const int r = blockIdx.x*256 + threadIdx.x;
  const size_t row64 = (size_t)r * 64;
#pragma unroll 1
  for (int p=0;p<2;p++){
    const void* src = p ? obs : ext;
    const int w1b = p?O_PXW1:O_PUW1, b1b = p?O_PXB1:O_PUB1;
    const int w2b = p?O_PXW2:O_PUW2, b2b = p?O_PXB2:O_PUB2;
    const int fb = p?(O_AW1+64):O_WIH; const int fs = p?128:64;
    const int bb = p?O_AB1:O_RNB;
    void* dstv = p ? ax_out : rnn_in;

    float u[16];
    if constexpr (MODE == 0){
      const uint4* up = (const uint4*)((const u16*)src + (size_t)r*16);
      uint4 v0 = up[0], v1 = up[1];
      u32 w[8] = {v0.x,v0.y,v0.z,v0.w,v1.x,v1.y,v1.z,v1.w};
#pragma unroll
      for (int i=0;i<8;i++){ u[2*i]=b2f((u16)(w[i]&0xffffu)); u[2*i+1]=b2f((u16)(w[i]>>16)); }
    } else {
      const float4* up = (const float4*)((const float*)src + (size_t)r*16);
#pragma unroll
      for (int i=0;i<4;i++){ float4 v = up[i]; u[4*i]=v.x; u[4*i+1]=v.y; u[4*i+2]=v.z; u[4*i+3]=v.w; }
    }

    float h[64];
#pragma unroll
    for (int j=0;j<64;j++){
      float a = W[b1b+j];
#pragma unroll
      for (int i=0;i<16;i++) a = fmaf(W[w1b + j*16 + i], u[i], a);
      h[j] = fmaxf(a, 0.0f);
    }
    float g[64];
#pragma unroll
    for (int j=0;j<64;j++){
      float a = W[b2b+j];
#pragma unroll
      for (int i=0;i<64;i++) a = fmaf(W[w2b + j*64 + i], h[i], a);
      g[j] = fmaxf(a, 0.0f);
    }
#pragma unroll
    for (int j=0;j<64;j++){
      float a = W[bb+j];
#pragma unroll
      for (int i=0;i<64;i++) a = fmaf(W[fb + j*fs + i], g[i], a);
      h[j] = a;
    }
    if constexpr (MODE == 0){
      u16* dst = (u16*)dstv + row64;
#pragma unroll
      for (int c=0;c<8;c++){
        u32 p0 = (u32)f2b(h[c*8+0]) | ((u32)f2b(h[c*8+1])<<16);
        u32 p1 = (u32)f2b(h[c*8+2]) | ((u32)f2b(h[c*8+3])<<16);
        u32 p2 = (u32)f2b(h[c*8+4]) | ((u32)f2b(h[c*8+5])<<16);
        u32 p3 = (u32)f2b(h[c*8+6]) | ((u32)f2b(h[c*8+7])<<16);
        ((uint4*)dst)[c] = make_uint4(p0,p1,p2,p3);
      }
    } else {
      float* dst = (float*)dstv + row64;
#pragma unroll
      for (int c=0;c<16;c++)
        ((float4*)dst)[c] = make_float4(h[4*c],h[4*c+1],h[4*c+2],h[4*c+3]);
    }
  }
}

// 16-term partial dot with 2 accumulator chains
__device__ __forceinline__ float dot16(const float* w, float4 a, float4 b, float4 c, float4 d){
  float s0=0.f, s1=0.f;
  s0=fmaf(w[0],a.x,s0);  s1=fmaf(w[1],a.y,s1);  s0=fmaf(w[2],a.z,s0);  s1=fmaf(w[3],a.w,s1);
  s0=fmaf(w[4],b.x,s0);  s1=fmaf(w[5],b.y,s1);  s0=fmaf(w[6],b.z,s0);  s1=fmaf(w[7],b.w,s1);
  s0=fmaf(w[8],c.x,s0);  s1=fmaf(w[9],c.y,s1);  s0=fmaf(w[10],c.z,s0); s1=fmaf(w[11],c.w,s1);
  s0=fmaf(w[12],d.x,s0); s1=fmaf(w[13],d.y,s1); s0=fmaf(w[14],d.z,s0); s1=fmaf(w[15],d.w,s1);
  return s0+s1;
}

// -------------------- K2: sequential RNN + a-layer (WG per batch lane) --------------------
template<int MODE>
__global__ __launch_bounds__(256) void k2_rnn(
  const float* __restrict__ W, void* __restrict__ outb)
{
  if (!live(W, MODE ? 2 : 1)) return;
  void* a_seq  = chunkp<MODE>(outb, 0);
  void* rnn_in = chunkp<MODE>(outb, 1);
  void* ax     = chunkp<MODE>(outb, 2);
  void* d_seq  = chunkp<MODE>(outb, 3);

  const int b = blockIdx.x;
  const int tid = threadIdx.x;
  const int q = tid>>6, j = tid&63;

  float wh[16], wa1[16], wa2[16];
#pragma unroll
  for (int i=0;i<16;i++){
    wh[i]  = W[O_WHH + j*64  + q*16 + i];
    wa1[i] = W[O_AW1 + j*128 + q*16 + i];   // d-half (cols 0..63)
    wa2[i] = W[O_AW2 + j*64  + q*16 + i];
  }
  const float ab2j = W[O_AB2 + j];

  __shared__ __align__(16) float h_lds[64];
  __shared__ __align__(16) float v_lds[64];
  __shared__ __align__(16) float red1[256], red2[256], red3[256];
  if (tid < 64){ h_lds[tid] = 0.f; v_lds[tid] = 0.f; }
  __syncthreads();

  const size_t brow = (size_t)b*64 + j;
  for (int t=0; t<L+2; ++t){
    const float4* hv = (const float4*)(&h_lds[q*16]);
    const float4* vv = (const float4*)(&v_lds[q*16]);
    float4 h0=hv[0], h1=hv[1], h2=hv[2], h3=hv[3];
    float4 v0=vv[0], v1=vv[1], v2=vv[2], v3=vv[3];
    red1[tid] = dot16(wh,  h0,h1,h2,h3);
    red2[tid] = dot16(wa1, h0,h1,h2,h3);
    red3[tid] = dot16(wa2, v0,v1,v2,v3);
    __syncthreads();
    if (q==0){
      if (t < L){
        const size_t idx = (size_t)t*(BB*64) + brow;
        float s = red1[j]+red1[64+j]+red1[128+j]+red1[192+j] + ldOne<MODE>(rnn_in, idx);
        float hn = tanhf_fast(s);
        h_lds[j] = hn;
        stOne<MODE>(d_seq, idx, hn);
      }
    } else if (q==1){
      if (t>=1 && t<=L){
        const size_t idx = (size_t)(t-1)*(BB*64) + brow;
        float s = red2[j]+red2[64+j]+red2[128+j]+red2[192+j] + ldOne<MODE>(ax, idx);
        v_lds[j] = tanhf_fast(s);
      }
    } else if (q==2){
      if (t>=2){
        const size_t idx = (size_t)(t-2)*(BB*64) + brow;
        float s = red3[j]+red3[64+j]+red3[128+j]+red3[192+j] + ab2j;
        stOne<MODE>(a_seq, idx, s);
      }
    }
    __syncthreads();
  }
}

// -------------------- K4: sequential latent scan (WG per batch lane) --------------------
template<int MODE>
__global__ __launch_bounds__(256,2) void k4_latent(
  const float* __restrict__ W,
  const void* __restrict__ noise, void* __restrict__ outb)
{
  if (!live(W, MODE ? 2 : 1)) return;
  void* amu = chunkp<MODE>(outb, 0);   // reads a_seq, writes state_mu
  void* lsc = chunkp<MODE>(outb, 1);   // writes state_logsigma
  void* zc  = chunkp<MODE>(outb, 2);   // writes sampled_state
  void* dsq = chunkp<MODE>(outb, 3);   // reads d_seq

  const int b = blockIdx.x;
  const int tid = threadIdx.x;

  __shared__ __align__(16) u32 wB[3*64*64];       // packed bf16 pairs, XOR-swizzled
  __shared__ __align__(16) float z_lds[64];
  __shared__ __align__(16) u32 tpo_pk[64];
  __shared__ __align__(16) u32 tpr_pk[64];
  __shared__ __align__(16) float out_lds[192];
  __shared__ __align__(16) u32 abuf[2][32];
  __shared__ __align__(16) u32 dbuf[2][32];
  __shared__ __align__(16) u32 ebuf[2][32];

  // stage-B weights (po_mu, po_ls, pr_mu) -> LDS packed+swizzled
  for (int x = tid; x < 3*64*64; x += 256){
    int m_ = x>>12, rem = x&4095, jj = rem>>6, i = rem&63;
    int src = (m_==0 ? O_POMU : (m_==1 ? O_POLS : O_PRMU)) + jj*128 + 2*i;
    u32 pk = (u32)f2b(W[src]) | ((u32)f2b(W[src+1])<<16);
    int c = i>>2, wi = i&3;
    wB[((m_<<6)+jj)*64 + ((c ^ (jj&7))<<2) + wi] = pk;
  }

  // stage-A weights -> registers, packed bf16 pairs (64 u32 z-part + 64 u32 a-part)
  const int o = tid;
  const int jr = o & 127;
  const int f1 = (o<128 ? O_POF1 : O_PRF1) + jr*128;
  const int f2 = (o<128 ? O_POF2 : O_PRF2) + jr*128;
  u32 wz1p[32], wz2p[32], wa1p[32], wa2p[32];
#pragma unroll
  for (int p=0;p<32;p++){
    wz1p[p] = (u32)f2b(W[f1+2*p])    | ((u32)f2b(W[f1+2*p+1])<<16);
    wz2p[p] = (u32)f2b(W[f2+2*p])    | ((u32)f2b(W[f2+2*p+1])<<16);
    wa1p[p] = (u32)f2b(W[f1+64+2*p]) | ((u32)f2b(W[f1+64+2*p+1])<<16);
    wa2p[p] = (u32)f2b(W[f2+64+2*p]) | ((u32)f2b(W[f2+64+2*p+1])<<16);
  }
  const float b1  = W[(o<128 ? O_POF1B : O_PRF1B) + jr];
  const float b2v = W[(o<128 ? O_POF2B : O_PRF2B) + jr];

  const int m = tid>>6, jb = tid&63;
  const float bB = (m==0) ? W[O_POMUB+jb] : (m==1 ? W[O_POLSB+jb] : (m==2 ? W[O_PRMUB+jb] : 0.f));

  if (tid < 64) z_lds[tid] = 0.f;
  if (tid < 32)       abuf[0][tid]    = ldpk<MODE>(amu,  (size_t)b*64, tid);
  else if (tid < 64)  dbuf[0][tid-32] = ldpk<MODE>(dsq,  (size_t)b*64, tid-32);
  else if (tid < 96)  ebuf[0][tid-64] = ldpk<MODE>(noise,(size_t)b*64, tid-64);
  __syncthreads();

  for (int t=0; t<L; ++t){
    const int cur = t&1;
    // ---- stage A ----
    float s1a=b1, s1b=0.f, s2a=b2v, s2b=0.f;
    const float2* z2 = (const float2*)z_lds;
    const u32* av = (o<128) ? abuf[cur] : dbuf[cur];
#pragma unroll
    for (int p=0;p<32;p++){
      float2 z = z2[p];
      s1a = fmaf(b2f((u16)(wz1p[p]&0xffffu)), z.x, s1a);
      s1b = fmaf(b2f((u16)(wz1p[p]>>16)),     z.y, s1b);
      s2a = fmaf(b2f((u16)(wz2p[p]&0xffffu)), z.x, s2a);
      s2b = fmaf(b2f((u16)(wz2p[p]>>16)),     z.y, s2b);
      u32 a = av[p];
      float alo = b2f((u16)(a&0xffffu)), ahi = b2f((u16)(a>>16));
      s1a = fmaf(b2f((u16)(wa1p[p]&0xffffu)), alo, s1a);
      s1b = fmaf(b2f((u16)(wa1p[p]>>16)),     ahi, s1b);
      s2a = fmaf(b2f((u16)(wa2p[p]&0xffffu)), alo, s2a);
      s2b = fmaf(b2f((u16)(wa2p[p]>>16)),     ahi, s2b);
    }
    float tv = tanhf_fast(s1a+s1b) * sigm_fast(s2a+s2b);
    float tvo = __shfl_xor(tv, 1);
    if (!(o&1)){
      u32 pk = (u32)f2b(tv) | ((u32)f2b(tvo)<<16);
      if (o < 128) tpo_pk[o>>1] = pk; else tpr_pk[(o-128)>>1] = pk;
    }
    __syncthreads();  // S1

    // ---- stage B: output matmuls (waves 0-2) + prefetch (wave 3) ----
    float acc = bB;
    if (m < 3){
      const u32* wrow = &wB[((m<<6)+jb)*64];
      const uint4* tsrc = (const uint4*)(m==2 ? tpr_pk : tpo_pk);
#pragma unroll
      for (int c=0;c<16;c++){
        const uint4 wv = *(const uint4*)(wrow + ((c ^ (jb&7))<<2));
        const uint4 t4 = tsrc[c];
        acc = dot2c(wv.x, t4.x, acc);
        acc = dot2c(wv.y, t4.y, acc);
        acc = dot2c(wv.z, t4.z, acc);
        acc = dot2c(wv.w, t4.w, acc);
      }
      if (m==1) out_lds[64+jb] = acc;
      else if (m==2) out_lds[128+jb] = acc;
    } else {
      if (t+1 < L){
        const size_t rb = ((size_t)(t+1)*BB + b)*64;
        const int nb = cur^1;
        if (jb < 32){ abuf[nb][jb] = ldpk<MODE>(amu, rb, jb); ebuf[nb][jb] = ldpk<MODE>(noise, rb, jb); }
        else dbuf[nb][jb-32] = ldpk<MODE>(dsq, rb, jb-32);
      }
    }
    __syncthreads();  // S2

    // ---- finish: z update (wave 0) ----
    if (m == 0){
      float ls  = out_lds[64+jb];
      float prm = out_lds[128+jb];
      float mu  = acc + prm;
      u32 ep = ebuf[cur][jb>>1];
      float eps = b2f((u16)((jb&1) ? (ep>>16) : (ep&0xffffu)));
      float z = fmaf(EXP2(ls*0.7213475204444817f), eps, mu);
      z_lds[jb] = z;
      const size_t idx = ((size_t)t*BB + b)*64 + jb;
      stOne<MODE>(amu, idx, mu);
      stOne<MODE>(lsc, idx, ls);
      stOne<MODE>(zc,  idx, z);
    }
    __syncthreads();  // S3
  }
}

extern "C" void kernel_launch(void* const* d_in, const int* in_sizes, int n_in,
                              void* d_out, int out_size, void* d_ws, size_t ws_size,
                              hipStream_t stream)
{
  (void)in_sizes; (void)n_in; (void)out_size; (void)ws_size;

  const void* ext   = d_in[0];
  const void* obs   = d_in[1];
  const void* noise = d_in[2];
  float* W = (float*)d_ws;

  kprobe<<<1,64,0,stream>>>((const u32*)ext, (u32*)W + O_FLAG);

#define K0ARGS \
    d_in[3],  d_in[4],  d_in[5],  d_in[6],  d_in[7],  d_in[8],  d_in[9],  d_in[10], \
    d_in[11], d_in[12], d_in[13], d_in[14], d_in[15], d_in[16], d_in[17], d_in[18], \
    d_in[19], d_in[20], d_in[21], d_in[22], d_in[23], d_in[24], d_in[25], d_in[26], \
    d_in[27], d_in[28], d_in[29], d_in[30], d_in[31], d_in[32], W

  k0_convert<0><<<64,256,0,stream>>>(K0ARGS);
  k0_convert<1><<<64,256,0,stream>>>(K0ARGS);
#undef K0ARGS

  k1_prep<0><<<NROWS/256, 256, 0, stream>>>(ext, obs, W, d_out);
  k1_prep<1><<<NROWS/256, 256, 0, stream>>>(ext, obs, W, d_out);

  k2_rnn<0><<<BB, 256, 0, stream>>>(W, d_out);
  k2_rnn<1><<<BB, 256, 0, stream>>>(W, d_out);

  k4_latent<0><<<BB, 256, 0, stream>>>(W, noise, d_out);
  k4_latent<1><<<BB, 256, 0, stream>>>(W, noise, d_out);
}

// Round 3
// 1846.527 us; speedup vs baseline: 3.5270x; 3.5270x over previous
//
#include <hip/hip_runtime.h>

typedef unsigned short u16;
typedef unsigned int u32;

#define L 512
#define BB 512
#define NROWS (L*BB)            // 262144
#define CH (NROWS*64)           // 16777216 elements per output chunk

// f32 weight offsets inside d_ws
enum {
  O_PUW1 = 0,
  O_PUB1 = 1024,
  O_PUW2 = 1088,
  O_PUB2 = 5184,
  O_PXW1 = 5248,
  O_PXB1 = 6272,
  O_PXW2 = 6336,
  O_PXB2 = 10432,
  O_WIH  = 10496,
  O_RNB  = 14592,   // bih + bhh
  O_WHH  = 14656,
  O_AW1  = 18752,   // 64x128
  O_AB1  = 26944,
  O_AW2  = 27008,
  O_AB2  = 31104,
  O_POF1 = 31168,   // 128x128
  O_POF1B= 47552,
  O_POF2 = 47680,
  O_POF2B= 64064,
  O_POMU = 64192,   // 64x128
  O_POMUB= 72384,
  O_POLS = 72448,
  O_POLSB= 80640,
  O_PRF1 = 80704,
  O_PRF1B= 97088,
  O_PRF2 = 97216,
  O_PRF2B= 113600,
  O_PRMU = 113728,
  O_PRMUB= 121920,
  O_FLAG = 121984,  // u32 dtype flag: 1 = bf16 device data, 2 = f32 device data
  O_END  = 121985
};

__device__ __forceinline__ float b2f(u16 x){ return __uint_as_float(((u32)x)<<16); }
__device__ __forceinline__ u16 f2b(float f){
  u32 u = __float_as_uint(f);
  u32 r = (u + 0x7fffu + ((u>>16)&1u)) >> 16;
  return (u16)r;
}

#if __has_builtin(__builtin_amdgcn_exp2f)
#define EXP2(x) __builtin_amdgcn_exp2f(x)
#else
#define EXP2(x) exp2f(x)
#endif
#if __has_builtin(__builtin_amdgcn_rcpf)
#define RCP(x) __builtin_amdgcn_rcpf(x)
#else
#define RCP(x) (1.0f/(x))
#endif

__device__ __forceinline__ float tanhf_fast(float x){
  float e = EXP2(x * 2.8853900817779268f);
  return 1.0f - 2.0f * RCP(e + 1.0f);
}
__device__ __forceinline__ float sigm_fast(float x){
  float e = EXP2(-1.4426950408889634f * x);
  return RCP(1.0f + e);
}

// ---- MFMA types & helpers ----
typedef __attribute__((ext_vector_type(8))) __bf16 bf16x8;
typedef __attribute__((ext_vector_type(4))) float f32x4;

__device__ __forceinline__ f32x4 mfma16(bf16x8 a, bf16x8 b, f32x4 c){
  return __builtin_amdgcn_mfma_f32_16x16x32_bf16(a, b, c, 0, 0, 0);
}
// B-fragment (or A-fragment) from 8 consecutive f32 weights, rounded to bf16
__device__ __forceinline__ bf16x8 wfrag(const float* W, int off){
  union { short s[8]; bf16x8 v; } c;
#pragma unroll
  for (int i=0;i<8;i++) c.s[i] = (short)f2b(W[off+i]);
  return c.v;
}
// A-frag read from a [16][64]-bf16 slot-swizzled LDS tile (8 x 16B slots/row)
__device__ __forceinline__ bf16x8 ldA64(const u32* buf, int r, int s){
  union { uint4 u; bf16x8 v; } c;
  c.u = ((const uint4*)buf)[r*8 + (s ^ (r&7))];
  return c.v;
}
// A-frag read from a [16][128]-bf16 slot-swizzled LDS tile (16 x 16B slots/row)
__device__ __forceinline__ bf16x8 ldT(const u32* buf, int r, int s){
  union { uint4 u; bf16x8 v; } c;
  c.u = ((const uint4*)buf)[r*16 + (s ^ (r&7))];
  return c.v;
}

// ---- MODE-generic load/store helpers (MODE 0: bf16 device data, 1: f32) ----
template<int MODE>
__device__ __forceinline__ float ldOne(const void* p, size_t i){
  if constexpr (MODE) return ((const float*)p)[i];
  else return b2f(((const u16*)p)[i]);
}
template<int MODE>
__device__ __forceinline__ void stOne(void* p, size_t i, float v){
  if constexpr (MODE) ((float*)p)[i] = v;
  else ((u16*)p)[i] = f2b(v);
}
template<int MODE>
__device__ __forceinline__ float wld(const void* p, int i){
  if constexpr (MODE) return ((const float*)p)[i];
  else return b2f(((const u16*)p)[i]);
}
template<int MODE>
__device__ __forceinline__ void* chunkp(void* out, int j){
  return (void*)((char*)out + (size_t)j * (size_t)CH * (MODE ? 4 : 2));
}
__device__ __forceinline__ bool live(const float* W, int tag){
  return ((const u32*)W)[O_FLAG] == (u32)tag;
}

// -------------------- probe: classify device dtype --------------------
__global__ void kprobe(const u32* __restrict__ ext, u32* __restrict__ flagp){
  if (threadIdx.x == 0 && blockIdx.x == 0){
    int cnt = 0;
    for (int i = 0; i < 1024; ++i){
      u32 e = (ext[i] >> 7) & 0xFFu;
      cnt += (e >= 110u && e <= 134u) ? 1 : 0;
    }
    flagp[0] = (cnt > 512) ? 1u : 2u;
  }
}

// -------------------- K0: weights -> f32 in ws --------------------
template<int MODE>
__global__ void k0_convert(
  const void* pu_w1, const void* pu_b1, const void* pu_w2, const void* pu_b2,
  const void* px_w1, const void* px_b1, const void* px_w2, const void* px_b2,
  const void* rnn_wih, const void* rnn_whh, const void* rnn_bih, const void* rnn_bhh,
  const void* a_w1, const void* a_b1, const void* a_w2, const void* a_b2,
  const void* po_f1, const void* po_f1b, const void* po_f2, const void* po_f2b,
  const void* po_mu, const void* po_mub, const void* po_ls, const void* po_lsb,
  const void* pr_f1, const void* pr_f1b, const void* pr_f2, const void* pr_f2b,
  const void* pr_mu, const void* pr_mub,
  float* W)
{
  if (!live(W, MODE ? 2 : 1)) return;
  const int g = blockIdx.x*blockDim.x + threadIdx.x;
  const int gs = gridDim.x*blockDim.x;
#define CVT(off, src, n) for (int i=g;i<(n);i+=gs) W[(off)+i] = wld<MODE>(src,i);
  CVT(O_PUW1, pu_w1, 1024)  CVT(O_PUB1, pu_b1, 64)
  CVT(O_PUW2, pu_w2, 4096)  CVT(O_PUB2, pu_b2, 64)
  CVT(O_PXW1, px_w1, 1024)  CVT(O_PXB1, px_b1, 64)
  CVT(O_PXW2, px_w2, 4096)  CVT(O_PXB2, px_b2, 64)
  CVT(O_WIH,  rnn_wih, 4096)
  CVT(O_WHH,  rnn_whh, 4096)
  CVT(O_AW1,  a_w1, 8192)   CVT(O_AB1, a_b1, 64)
  CVT(O_AW2,  a_w2, 4096)   CVT(O_AB2, a_b2, 64)
  CVT(O_POF1, po_f1, 16384) CVT(O_POF1B, po_f1b, 128)
  CVT(O_POF2, po_f2, 16384) CVT(O_POF2B, po_f2b, 128)
  CVT(O_POMU, po_mu, 8192)  CVT(O_POMUB, po_mub, 64)
  CVT(O_POLS, po_ls, 8192)  CVT(O_POLSB, po_lsb, 64)
  CVT(O_PRF1, pr_f1, 16384) CVT(O_PRF1B, pr_f1b, 128)
  CVT(O_PRF2, pr_f2, 16384) CVT(O_PRF2B, pr_f2b, 128)
  CVT(O_PRMU, pr_mu, 8192)  CVT(O_PRMUB, pr_mub, 64)
#undef CVT
  for (int i=g;i<64;i+=gs) W[O_RNB+i] = wld<MODE>(rnn_bih,i) + wld<MODE>(rnn_bhh,i);
}

// -------------------- K1: parallel prep (thread-per-row) --------------------
template<int MODE>
__global__ __launch_bounds__(256) void k1_prep(
  const void* __restrict__ ext, const void* __restrict__ obs,
  const float* __restrict__ W, void* __restrict__ outb)
{
  if (!live(W, MODE ? 2 : 1)) return;
  void* rnn_in = chunkp<MODE>(outb, 1);
  void* ax_out = chunkp<MODE>(outb, 2);

  const int r = blockIdx.x*256 + threadIdx.x;
  const size_t row64 = (size_t)r * 64;
#pragma unroll 1
  for (int p=0;p<2;p++){
    const void* src = p ? obs : ext;
    const int w1b = p?O_PXW1:O_PUW1, b1b = p?O_PXB1:O_PUB1;
    const int w2b = p?O_PXW2:O_PUW2, b2b = p?O_PXB2:O_PUB2;
    const int fb = p?(O_AW1+64):O_WIH; const int fs = p?128:64;
    const int bb = p?O_AB1:O_RNB;
    void* dstv = p ? ax_out : rnn_in;

    float u[16];
    if constexpr (MODE == 0){
      const uint4* up = (const uint4*)((const u16*)src + (size_t)r*16);
      uint4 v0 = up[0], v1 = up[1];
      u32 w[8] = {v0.x,v0.y,v0.z,v0.w,v1.x,v1.y,v1.z,v1.w};
#pragma unroll
      for (int i=0;i<8;i++){ u[2*i]=b2f((u16)(w[i]&0xffffu)); u[2*i+1]=b2f((u16)(w[i]>>16)); }
    } else {
      const float4* up = (const float4*)((const float*)src + (size_t)r*16);
#pragma unroll
      for (int i=0;i<4;i++){ float4 v = up[i]; u[4*i]=v.x; u[4*i+1]=v.y; u[4*i+2]=v.z; u[4*i+3]=v.w; }
    }

    float h[64];
#pragma unroll
    for (int j=0;j<64;j++){
      float a = W[b1b+j];
#pragma unroll
      for (int i=0;i<16;i++) a = fmaf(W[w1b + j*16 + i], u[i], a);
      h[j] = fmaxf(a, 0.0f);
    }
    float g[64];
#pragma unroll
    for (int j=0;j<64;j++){
      float a = W[b2b+j];
#pragma unroll
      for (int i=0;i<64;i++) a = fmaf(W[w2b + j*64 + i], h[i], a);
      g[j] = fmaxf(a, 0.0f);
    }
#pragma unroll
    for (int j=0;j<64;j++){
      float a = W[bb+j];
#pragma unroll
      for (int i=0;i<64;i++) a = fmaf(W[fb + j*fs + i], g[i], a);
      h[j] = a;
    }
    if constexpr (MODE == 0){
      u16* dst = (u16*)dstv + row64;
#pragma unroll
      for (int c=0;c<8;c++){
        u32 p0 = (u32)f2b(h[c*8+0]) | ((u32)f2b(h[c*8+1])<<16);
        u32 p1 = (u32)f2b(h[c*8+2]) | ((u32)f2b(h[c*8+3])<<16);
        u32 p2 = (u32)f2b(h[c*8+4]) | ((u32)f2b(h[c*8+5])<<16);
        u32 p3 = (u32)f2b(h[c*8+6]) | ((u32)f2b(h[c*8+7])<<16);
        ((uint4*)dst)[c] = make_uint4(p0,p1,p2,p3);
      }
    } else {
      float* dst = (float*)dstv + row64;
#pragma unroll
      for (int c=0;c<16;c++)
        ((float4*)dst)[c] = make_float4(h[4*c],h[4*c+1],h[4*c+2],h[4*c+3]);
    }
  }
}

// 16-term partial dot with 2 accumulator chains
__device__ __forceinline__ float dot16(const float* w, float4 a, float4 b, float4 c, float4 d){
  float s0=0.f, s1=0.f;
  s0=fmaf(w[0],a.x,s0);  s1=fmaf(w[1],a.y,s1);  s0=fmaf(w[2],a.z,s0);  s1=fmaf(w[3],a.w,s1);
  s0=fmaf(w[4],b.x,s0);  s1=fmaf(w[5],b.y,s1);  s0=fmaf(w[6],b.z,s0);  s1=fmaf(w[7],b.w,s1);
  s0=fmaf(w[8],c.x,s0);  s1=fmaf(w[9],c.y,s1);  s0=fmaf(w[10],c.z,s0); s1=fmaf(w[11],c.w,s1);
  s0=fmaf(w[12],d.x,s0); s1=fmaf(w[13],d.y,s1); s0=fmaf(w[14],d.z,s0); s1=fmaf(w[15],d.w,s1);
  return s0+s1;
}

// -------------------- K2: sequential RNN + a-layer (WG per batch lane) --------------------
template<int MODE>
__global__ __launch_bounds__(256) void k2_rnn(
  const float* __restrict__ W, void* __restrict__ outb)
{
  if (!live(W, MODE ? 2 : 1)) return;
  void* a_seq  = chunkp<MODE>(outb, 0);
  void* rnn_in = chunkp<MODE>(outb, 1);
  void* ax     = chunkp<MODE>(outb, 2);
  void* d_seq  = chunkp<MODE>(outb, 3);

  const int b = blockIdx.x;
  const int tid = threadIdx.x;
  const int q = tid>>6, j = tid&63;

  float wh[16], wa1[16], wa2[16];
#pragma unroll
  for (int i=0;i<16;i++){
    wh[i]  = W[O_WHH + j*64  + q*16 + i];
    wa1[i] = W[O_AW1 + j*128 + q*16 + i];   // d-half (cols 0..63)
    wa2[i] = W[O_AW2 + j*64  + q*16 + i];
  }
  const float ab2j = W[O_AB2 + j];

  __shared__ __align__(16) float h_lds[64];
  __shared__ __align__(16) float v_lds[64];
  __shared__ __align__(16) float red1[256], red2[256], red3[256];
  if (tid < 64){ h_lds[tid] = 0.f; v_lds[tid] = 0.f; }
  __syncthreads();

  const size_t brow = (size_t)b*64 + j;
  for (int t=0; t<L+2; ++t){
    const float4* hv = (const float4*)(&h_lds[q*16]);
    const float4* vv = (const float4*)(&v_lds[q*16]);
    float4 h0=hv[0], h1=hv[1], h2=hv[2], h3=hv[3];
    float4 v0=vv[0], v1=vv[1], v2=vv[2], v3=vv[3];
    red1[tid] = dot16(wh,  h0,h1,h2,h3);
    red2[tid] = dot16(wa1, h0,h1,h2,h3);
    red3[tid] = dot16(wa2, v0,v1,v2,v3);
    __syncthreads();
    if (q==0){
      if (t < L){
        const size_t idx = (size_t)t*(BB*64) + brow;
        float s = red1[j]+red1[64+j]+red1[128+j]+red1[192+j] + ldOne<MODE>(rnn_in, idx);
        float hn = tanhf_fast(s);
        h_lds[j] = hn;
        stOne<MODE>(d_seq, idx, hn);
      }
    } else if (q==1){
      if (t>=1 && t<=L){
        const size_t idx = (size_t)(t-1)*(BB*64) + brow;
        float s = red2[j]+red2[64+j]+red2[128+j]+red2[192+j] + ldOne<MODE>(ax, idx);
        v_lds[j] = tanhf_fast(s);
      }
    } else if (q==2){
      if (t>=2){
        const size_t idx = (size_t)(t-2)*(BB*64) + brow;
        float s = red3[j]+red3[64+j]+red3[128+j]+red3[192+j] + ab2j;
        stOne<MODE>(a_seq, idx, s);
      }
    }
    __syncthreads();
  }
}

// -------------------- K4M: MFMA latent scan (WG per 16 batch lanes) --------------------
// 32 WGs x 512 threads (8 waves). Stage A: 4 fc matrices (po_fc1/fc2, pr_fc1/fc2),
// each wave owns 32 neurons of BOTH fc1+fc2 of one DBlock -> local tanh*sigm.
// Stage B: waves 0..5 compute po_mu/po_ls/pr_mu halves; waves 6,7 prefetch t+1.
template<int MODE>
__global__ __launch_bounds__(512,2) void k4m(
  const float* __restrict__ W,
  const void* __restrict__ noise, void* __restrict__ outb)
{
  if (!live(W, MODE ? 2 : 1)) return;
  void* amu = chunkp<MODE>(outb, 0);   // reads a_seq, writes state_mu
  void* lsc = chunkp<MODE>(outb, 1);   // writes state_logsigma
  void* zc  = chunkp<MODE>(outb, 2);   // writes sampled_state
  void* dsq = chunkp<MODE>(outb, 3);   // reads d_seq

  const int G = blockIdx.x;
  const int tid = threadIdx.x;
  const int wave = tid>>6, lane = tid&63;
  const int lr = lane&15, lg = lane>>4;

  __shared__ __align__(16) u32 Zbuf[512];          // [16][64] bf16, 16B-slot swizzled
  __shared__ __align__(16) u32 Abuf[2][512];       // a_t   (same layout)
  __shared__ __align__(16) u32 Dbuf[2][512];       // d_t
  __shared__ __align__(16) u32 Ebuf[2][1024];      // eps as f32 bits, [16][64] plain
  __shared__ __align__(16) u32 Tpo[1024];          // t_po [16][128] bf16 swizzled
  __shared__ __align__(16) u32 Tpr[1024];
  __shared__ __align__(16) float Obuf[3*1024];     // po_mu/po_ls/pr_mu outs, [16][64] f32, slot-swizzled by b
  __shared__ float bmu[64], bls[64];

  const bool isPo = wave < 4;
  const int wq = wave & 3;
  const int jA = wq*32;

  // ---- stage-A weight fragments (all 8 waves) ----
  const int of1 = isPo ? O_POF1 : O_PRF1;
  const int of2 = isPo ? O_POF2 : O_PRF2;
  bf16x8 wf1[2][4], wf2[2][4];
  float bA1[2], bA2[2];
#pragma unroll
  for (int nt=0; nt<2; ++nt){
    const int j = jA + nt*16 + lr;
    bA1[nt] = W[(isPo?O_POF1B:O_PRF1B) + j];
    bA2[nt] = W[(isPo?O_POF2B:O_PRF2B) + j];
#pragma unroll
    for (int kk=0; kk<4; ++kk){
      const int k = kk*32 + lg*8;
      wf1[nt][kk] = wfrag(W, of1 + j*128 + k);
      wf2[nt][kk] = wfrag(W, of2 + j*128 + k);
    }
  }
  // ---- stage-B weight fragments (waves 0..5) ----
  const int mb = wave>>1, nh = wave&1;
  bf16x8 wb[2][4];
  if (wave < 6){
    const int ob = (mb==0) ? O_POMU : (mb==1 ? O_POLS : O_PRMU);
#pragma unroll
    for (int nt=0; nt<2; ++nt)
#pragma unroll
      for (int kk=0; kk<4; ++kk){
        const int j = nh*32 + nt*16 + lr;
        const int k = kk*32 + lg*8;
        wb[nt][kk] = wfrag(W, ob + j*128 + k);
      }
  }

  // ---- init: biases, zero z, initial prefetch ----
  if (tid < 64){ bmu[tid] = W[O_POMUB+tid] + W[O_PRMUB+tid]; bls[tid] = W[O_POLSB+tid]; }
  Zbuf[tid & 511] = 0;

  const int pr_ = lane>>2, pc = lane&3;      // prefetch row / col-group
  float4 pA[4], pE[4]; uint4 qA[2], qE[2];

  auto pf_issue = [&](int tt){
    const size_t rowb = ((size_t)tt*BB + G*16 + pr_)*64;
    const void* gsrc = (wave==6) ? amu : dsq;
    if constexpr (MODE){
      const float4* sp = (const float4*)((const float*)gsrc + rowb) + pc*4;
#pragma unroll
      for (int i=0;i<4;i++) pA[i] = sp[i];
      if (wave==6){
        const float4* ep = (const float4*)((const float*)noise + rowb) + pc*4;
#pragma unroll
        for (int i=0;i<4;i++) pE[i] = ep[i];
      }
    } else {
      const uint4* sp = (const uint4*)((const u16*)gsrc + rowb) + pc*2;
      qA[0] = sp[0]; qA[1] = sp[1];
      if (wave==6){
        const uint4* ep = (const uint4*)((const u16*)noise + rowb) + pc*2;
        qE[0] = ep[0]; qE[1] = ep[1];
      }
    }
  };
  auto pf_write = [&](int buf){
    u32* dst = (wave==6) ? Abuf[buf] : Dbuf[buf];
    uint4* d0 = (uint4*)dst + (pr_*8 + ((pc*2  ) ^ (pr_&7)));
    uint4* d1 = (uint4*)dst + (pr_*8 + ((pc*2+1) ^ (pr_&7)));
    if constexpr (MODE){
      u32 w[8];
#pragma unroll
      for (int i=0;i<4;i++){
        w[2*i]   = (u32)f2b(pA[i].x) | ((u32)f2b(pA[i].y)<<16);
        w[2*i+1] = (u32)f2b(pA[i].z) | ((u32)f2b(pA[i].w)<<16);
      }
      *d0 = make_uint4(w[0],w[1],w[2],w[3]);
      *d1 = make_uint4(w[4],w[5],w[6],w[7]);
      if (wave==6){
        uint4* eb = (uint4*)Ebuf[buf] + (pr_*16 + pc*4);
#pragma unroll
        for (int i=0;i<4;i++){
          union { float4 f; uint4 u; } cv; cv.f = pE[i];
          eb[i] = cv.u;
        }
      }
    } else {
      *d0 = qA[0]; *d1 = qA[1];
      if (wave==6){
        u32* Eb = Ebuf[buf] + pr_*64 + pc*16;
        u32 ww[4] = {qE[0].x, qE[0].y, qE[0].z, qE[0].w};
#pragma unroll
        for (int i=0;i<4;i++){ Eb[2*i] = ww[i]<<16; Eb[2*i+1] = ww[i] & 0xffff0000u; }
        u32 w2[4] = {qE[1].x, qE[1].y, qE[1].z, qE[1].w};
#pragma unroll
        for (int i=0;i<4;i++){ Eb[8+2*i] = w2[i]<<16; Eb[8+2*i+1] = w2[i] & 0xffff0000u; }
      }
    }
  };

  if (wave >= 6){ pf_issue(0); pf_write(0); }
  __syncthreads();

  for (int t=0; t<L; ++t){
    const int cur = t&1, nb = cur^1;
    if (wave >= 6 && t+1 < L) pf_issue(t+1);   // issue early; written after S2

    // ---- stage A: all 8 waves, 16 MFMA each ----
    const u32* ADc = isPo ? Abuf[cur] : Dbuf[cur];
    bf16x8 a0 = ldA64(Zbuf, lr, lg);
    bf16x8 a1 = ldA64(Zbuf, lr, 4+lg);
    bf16x8 a2 = ldA64(ADc,  lr, lg);
    bf16x8 a3 = ldA64(ADc,  lr, 4+lg);
    f32x4 c1[2], c2[2];
#pragma unroll
    for (int nt=0; nt<2; ++nt){
      f32x4 i1 = {bA1[nt],bA1[nt],bA1[nt],bA1[nt]};
      f32x4 i2 = {bA2[nt],bA2[nt],bA2[nt],bA2[nt]};
      i1 = mfma16(a0, wf1[nt][0], i1);
      i1 = mfma16(a1, wf1[nt][1], i1);
      i1 = mfma16(a2, wf1[nt][2], i1);
      i1 = mfma16(a3, wf1[nt][3], i1);
      i2 = mfma16(a0, wf2[nt][0], i2);
      i2 = mfma16(a1, wf2[nt][1], i2);
      i2 = mfma16(a2, wf2[nt][2], i2);
      i2 = mfma16(a3, wf2[nt][3], i2);
      c1[nt] = i1; c2[nt] = i2;
    }
    // t = tanh(fc1)*sigm(fc2), write bf16 into T (A-operand layout, swizzled)
    u16* Td = (u16*)(isPo ? Tpo : Tpr);
#pragma unroll
    for (int nt=0; nt<2; ++nt)
#pragma unroll
      for (int r=0; r<4; ++r){
        float tv = tanhf_fast(c1[nt][r]) * sigm_fast(c2[nt][r]);
        const int j = jA + nt*16 + lr;
        const int b = lg*4 + r;
        Td[b*128 + (((j>>3)^(b&7))<<3) + (j&7)] = f2b(tv);
      }
    __syncthreads();  // S2: T ready

    // ---- stage B: waves 0..5 output matmuls; waves 6,7 write prefetched ----
    if (wave < 6){
      const u32* Ts = (mb==2) ? Tpr : Tpo;
      bf16x8 t0 = ldT(Ts, lr, lg);
      bf16x8 t1 = ldT(Ts, lr, 4+lg);
      bf16x8 t2 = ldT(Ts, lr, 8+lg);
      bf16x8 t3 = ldT(Ts, lr, 12+lg);
      f32x4 d0 = {0.f,0.f,0.f,0.f}, d1 = {0.f,0.f,0.f,0.f};
      d0 = mfma16(t0, wb[0][0], d0);
      d0 = mfma16(t1, wb[0][1], d0);
      d0 = mfma16(t2, wb[0][2], d0);
      d0 = mfma16(t3, wb[0][3], d0);
      d1 = mfma16(t0, wb[1][0], d1);
      d1 = mfma16(t1, wb[1][1], d1);
      d1 = mfma16(t2, wb[1][2], d1);
      d1 = mfma16(t3, wb[1][3], d1);
      float* Od = &Obuf[mb*1024];
#pragma unroll
      for (int r=0; r<4; ++r){
        const int b = lg*4 + r;
        const int j0 = nh*32 + lr;
        const int j1 = nh*32 + 16 + lr;
        Od[b*64 + (((j0>>2)^(b&7))<<2) + (j0&3)] = d0[r];
        Od[b*64 + (((j1>>2)^(b&7))<<2) + (j1&3)] = d1[r];
      }
    } else if (t+1 < L){
      pf_write(nb);
    }
    __syncthreads();  // S3: outs + next a/d/eps ready

    // ---- z update: 512 threads cover 16x64, 2 outputs each ----
    {
      const int b = tid>>5;
      const int j = (tid&31)*2;
      const int sidx = b*64 + (((j>>2)^(b&7))<<2) + (j&3);
      float2 vpo = *(const float2*)&Obuf[0*1024 + sidx];
      float2 vls = *(const float2*)&Obuf[1*1024 + sidx];
      float2 vpr = *(const float2*)&Obuf[2*1024 + sidx];
      float2 bm = *(const float2*)&bmu[j];
      float2 bl = *(const float2*)&bls[j];
      float e0 = __uint_as_float(Ebuf[cur][b*64 + j]);
      float e1 = __uint_as_float(Ebuf[cur][b*64 + j + 1]);
      float mu0 = vpo.x + vpr.x + bm.x;
      float mu1 = vpo.y + vpr.y + bm.y;
      float ls0 = vls.x + bl.x;
      float ls1 = vls.y + bl.y;
      float z0 = fmaf(EXP2(ls0*0.7213475204444817f), e0, mu0);
      float z1 = fmaf(EXP2(ls1*0.7213475204444817f), e1, mu1);
      // write z into Zbuf (bf16 pair, swizzled slot)
      Zbuf[b*32 + (((j>>3)^(b&7))<<2) + ((j&7)>>1)] = (u32)f2b(z0) | ((u32)f2b(z1)<<16);
      // global outputs
      const size_t idx = ((size_t)t*BB + G*16 + b)*64 + j;
      if constexpr (MODE){
        *(float2*)((float*)amu + idx) = make_float2(mu0, mu1);
        *(float2*)((float*)lsc + idx) = make_float2(ls0, ls1);
        *(float2*)((float*)zc  + idx) = make_float2(z0, z1);
      } else {
        *(u32*)((u16*)amu + idx) = (u32)f2b(mu0) | ((u32)f2b(mu1)<<16);
        *(u32*)((u16*)lsc + idx) = (u32)f2b(ls0) | ((u32)f2b(ls1)<<16);
        *(u32*)((u16*)zc  + idx) = (u32)f2b(z0)  | ((u32)f2b(z1)<<16);
      }
    }
    __syncthreads();  // S4: z ready for next step
  }
}

extern "C" void kernel_launch(void* const* d_in, const int* in_sizes, int n_in,
                              void* d_out, int out_size, void* d_ws, size_t ws_size,
                              hipStream_t stream)
{
  (void)in_sizes; (void)n_in; (void)out_size; (void)ws_size;

  const void* ext   = d_in[0];
  const void* obs   = d_in[1];
  const void* noise = d_in[2];
  float* W = (float*)d_ws;

  kprobe<<<1,64,0,stream>>>((const u32*)ext, (u32*)W + O_FLAG);

#define K0ARGS \
    d_in[3],  d_in[4],  d_in[5],  d_in[6],  d_in[7],  d_in[8],  d_in[9],  d_in[10], \
    d_in[11], d_in[12], d_in[13], d_in[14], d_in[15], d_in[16], d_in[17], d_in[18], \
    d_in[19], d_in[20], d_in[21], d_in[22], d_in[23], d_in[24], d_in[25], d_in[26], \
    d_in[27], d_in[28], d_in[29], d_in[30], d_in[31], d_in[32], W

  k0_convert<0><<<64,256,0,stream>>>(K0ARGS);
  k0_convert<1><<<64,256,0,stream>>>(K0ARGS);
#undef K0ARGS

  k1_prep<0><<<NROWS/256, 256, 0, stream>>>(ext, obs, W, d_out);
  k1_prep<1><<<NROWS/256, 256, 0, stream>>>(ext, obs, W, d_out);

  k2_rnn<0><<<BB, 256, 0, stream>>>(W, d_out);
  k2_rnn<1><<<BB, 256, 0, stream>>>(W, d_out);

  k4m<0><<<32, 512, 0, stream>>>(W, noise, d_out);
  k4m<1><<<32, 512, 0, stream>>>(W, noise, d_out);
}

// Round 4
// 1099.509 us; speedup vs baseline: 5.9233x; 1.6794x over previous
//
#include <hip/hip_runtime.h>

typedef unsigned short u16;
typedef unsigned int u32;

#define L 512
#define BB 512
#define NROWS (L*BB)            // 262144
#define CH (NROWS*64)           // 16777216 elements per output chunk

// f32 weight offsets inside d_ws
enum {
  O_PUW1 = 0,
  O_PUB1 = 1024,
  O_PUW2 = 1088,
  O_PUB2 = 5184,
  O_PXW1 = 5248,
  O_PXB1 = 6272,
  O_PXW2 = 6336,
  O_PXB2 = 10432,
  O_WIH  = 10496,
  O_RNB  = 14592,   // bih + bhh
  O_WHH  = 14656,
  O_AW1  = 18752,   // 64x128
  O_AB1  = 26944,
  O_AW2  = 27008,
  O_AB2  = 31104,
  O_POF1 = 31168,   // 128x128
  O_POF1B= 47552,
  O_POF2 = 47680,
  O_POF2B= 64064,
  O_POMU = 64192,   // 64x128
  O_POMUB= 72384,
  O_POLS = 72448,
  O_POLSB= 80640,
  O_PRF1 = 80704,
  O_PRF1B= 97088,
  O_PRF2 = 97216,
  O_PRF2B= 113600,
  O_PRMU = 113728,
  O_PRMUB= 121920,
  O_FLAG = 121984,  // u32 dtype flag: 1 = bf16 device data, 2 = f32 device data
  O_HB   = 122000   // bf16-packed weight region starts here (u16 units below)
};
// u16 offsets within Wh = (u16*)(W + O_HB)
enum {
  HU1 = 0,       // pu_w1  [64][16]
  HU2 = 1024,    // pu_w2  [64][64]
  HX1 = 5120,    // px_w1  [64][16]
  HX2 = 6144,    // px_w2  [64][64]
  HW3U= 10240,   // rnn_wih [64][64]
  HW3X= 14336,   // a_w1[:,64:] repacked [64][64]
  HEND= 18432
};

__device__ __forceinline__ float b2f(u16 x){ return __uint_as_float(((u32)x)<<16); }
__device__ __forceinline__ u16 f2b(float f){
  u32 u = __float_as_uint(f);
  u32 r = (u + 0x7fffu + ((u>>16)&1u)) >> 16;
  return (u16)r;
}

#if __has_builtin(__builtin_amdgcn_exp2f)
#define EXP2(x) __builtin_amdgcn_exp2f(x)
#else
#define EXP2(x) exp2f(x)
#endif
#if __has_builtin(__builtin_amdgcn_rcpf)
#define RCP(x) __builtin_amdgcn_rcpf(x)
#else
#define RCP(x) (1.0f/(x))
#endif

__device__ __forceinline__ float tanhf_fast(float x){
  float e = EXP2(x * 2.8853900817779268f);
  return 1.0f - 2.0f * RCP(e + 1.0f);
}
__device__ __forceinline__ float sigm_fast(float x){
  float e = EXP2(-1.4426950408889634f * x);
  return RCP(1.0f + e);
}

// ---- MFMA types & helpers ----
typedef __attribute__((ext_vector_type(8))) __bf16 bf16x8;
typedef __attribute__((ext_vector_type(4))) float f32x4;

__device__ __forceinline__ f32x4 mfma16(bf16x8 a, bf16x8 b, f32x4 c){
  return __builtin_amdgcn_mfma_f32_16x16x32_bf16(a, b, c, 0, 0, 0);
}
// B-fragment (or A-fragment) from 8 consecutive f32 weights, rounded to bf16
__device__ __forceinline__ bf16x8 wfrag(const float* W, int off){
  union { short s[8]; bf16x8 v; } c;
#pragma unroll
  for (int i=0;i<8;i++) c.s[i] = (short)f2b(W[off+i]);
  return c.v;
}
// 8 packed bf16 from u16 memory (16B aligned)
__device__ __forceinline__ bf16x8 load16(const u16* p){
  union { uint4 u; bf16x8 v; } c;
  c.u = *(const uint4*)p;
  return c.v;
}
__device__ __forceinline__ bf16x8 zfrag(){
  union { uint4 u; bf16x8 v; } c;
  c.u = make_uint4(0,0,0,0);
  return c.v;
}
// A-frag read from a [16][64]-bf16 slot-swizzled LDS tile (8 x 16B slots/row)
__device__ __forceinline__ bf16x8 ldA64(const u32* buf, int r, int s){
  union { uint4 u; bf16x8 v; } c;
  c.u = ((const uint4*)buf)[r*8 + (s ^ (r&7))];
  return c.v;
}
// A-frag read from a [16][128]-bf16 slot-swizzled LDS tile (16 x 16B slots/row)
__device__ __forceinline__ bf16x8 ldT(const u32* buf, int r, int s){
  union { uint4 u; bf16x8 v; } c;
  c.u = ((const uint4*)buf)[r*16 + (s ^ (r&7))];
  return c.v;
}

// ---- MODE-generic load/store helpers (MODE 0: bf16 device data, 1: f32) ----
template<int MODE>
__device__ __forceinline__ float ldOne(const void* p, size_t i){
  if constexpr (MODE) return ((const float*)p)[i];
  else return b2f(((const u16*)p)[i]);
}
template<int MODE>
__device__ __forceinline__ void stOne(void* p, size_t i, float v){
  if constexpr (MODE) ((float*)p)[i] = v;
  else ((u16*)p)[i] = f2b(v);
}
template<int MODE>
__device__ __forceinline__ float wld(const void* p, int i){
  if constexpr (MODE) return ((const float*)p)[i];
  else return b2f(((const u16*)p)[i]);
}
template<int MODE>
__device__ __forceinline__ u16 hld(const void* p, int i){
  if constexpr (MODE) return f2b(((const float*)p)[i]);
  else return ((const u16*)p)[i];
}
template<int MODE>
__device__ __forceinline__ void* chunkp(void* out, int j){
  return (void*)((char*)out + (size_t)j * (size_t)CH * (MODE ? 4 : 2));
}
__device__ __forceinline__ bool live(const float* W, int tag){
  return ((const u32*)W)[O_FLAG] == (u32)tag;
}

// -------------------- probe: classify device dtype --------------------
__global__ void kprobe(const u32* __restrict__ ext, u32* __restrict__ flagp){
  if (threadIdx.x == 0 && blockIdx.x == 0){
    int cnt = 0;
    for (int i = 0; i < 1024; ++i){
      u32 e = (ext[i] >> 7) & 0xFFu;
      cnt += (e >= 110u && e <= 134u) ? 1 : 0;
    }
    flagp[0] = (cnt > 512) ? 1u : 2u;
  }
}

// -------------------- K0: weights -> f32 (+ bf16 packs) in ws --------------------
template<int MODE>
__global__ void k0_convert(
  const void* pu_w1, const void* pu_b1, const void* pu_w2, const void* pu_b2,
  const void* px_w1, const void* px_b1, const void* px_w2, const void* px_b2,
  const void* rnn_wih, const void* rnn_whh, const void* rnn_bih, const void* rnn_bhh,
  const void* a_w1, const void* a_b1, const void* a_w2, const void* a_b2,
  const void* po_f1, const void* po_f1b, const void* po_f2, const void* po_f2b,
  const void* po_mu, const void* po_mub, const void* po_ls, const void* po_lsb,
  const void* pr_f1, const void* pr_f1b, const void* pr_f2, const void* pr_f2b,
  const void* pr_mu, const void* pr_mub,
  float* W)
{
  if (!live(W, MODE ? 2 : 1)) return;
  const int g = blockIdx.x*blockDim.x + threadIdx.x;
  const int gs = gridDim.x*blockDim.x;
#define CVT(off, src, n) for (int i=g;i<(n);i+=gs) W[(off)+i] = wld<MODE>(src,i);
  CVT(O_PUW1, pu_w1, 1024)  CVT(O_PUB1, pu_b1, 64)
  CVT(O_PUW2, pu_w2, 4096)  CVT(O_PUB2, pu_b2, 64)
  CVT(O_PXW1, px_w1, 1024)  CVT(O_PXB1, px_b1, 64)
  CVT(O_PXW2, px_w2, 4096)  CVT(O_PXB2, px_b2, 64)
  CVT(O_WIH,  rnn_wih, 4096)
  CVT(O_WHH,  rnn_whh, 4096)
  CVT(O_AW1,  a_w1, 8192)   CVT(O_AB1, a_b1, 64)
  CVT(O_AW2,  a_w2, 4096)   CVT(O_AB2, a_b2, 64)
  CVT(O_POF1, po_f1, 16384) CVT(O_POF1B, po_f1b, 128)
  CVT(O_POF2, po_f2, 16384) CVT(O_POF2B, po_f2b, 128)
  CVT(O_POMU, po_mu, 8192)  CVT(O_POMUB, po_mub, 64)
  CVT(O_POLS, po_ls, 8192)  CVT(O_POLSB, po_lsb, 64)
  CVT(O_PRF1, pr_f1, 16384) CVT(O_PRF1B, pr_f1b, 128)
  CVT(O_PRF2, pr_f2, 16384) CVT(O_PRF2B, pr_f2b, 128)
  CVT(O_PRMU, pr_mu, 8192)  CVT(O_PRMUB, pr_mub, 64)
#undef CVT
  for (int i=g;i<64;i+=gs) W[O_RNB+i] = wld<MODE>(rnn_bih,i) + wld<MODE>(rnn_bhh,i);

  // bf16-packed weights for k1m (read directly from sources)
  u16* Wh = (u16*)(W + O_HB);
  for (int i=g;i<1024;i+=gs) Wh[HU1+i] = hld<MODE>(pu_w1,i);
  for (int i=g;i<4096;i+=gs) Wh[HU2+i] = hld<MODE>(pu_w2,i);
  for (int i=g;i<1024;i+=gs) Wh[HX1+i] = hld<MODE>(px_w1,i);
  for (int i=g;i<4096;i+=gs) Wh[HX2+i] = hld<MODE>(px_w2,i);
  for (int i=g;i<4096;i+=gs) Wh[HW3U+i] = hld<MODE>(rnn_wih,i);
  for (int i=g;i<4096;i+=gs){
    int j = i>>6, c = i&63;
    Wh[HW3X+i] = hld<MODE>(a_w1, j*128 + 64 + c);
  }
}

// -------------------- K1M: MFMA prep (wave-private tiles, no barriers) --------------------
// Each wave: 16-row tiles. L1: [16x16]@[64x16]^T (K padded to 32, 4 MFMA);
// L2: [16x64]@[64x64]^T (8 MFMA); L3: same (8 MFMA). C/D->A relayout via
// wave-private swizzled LDS tile; coalesced stores through same tile.
#define K1_NT 4
template<int MODE>
__global__ __launch_bounds__(512) void k1m(
  const void* __restrict__ ext, const void* __restrict__ obs,
  const float* __restrict__ W, void* __restrict__ outb)
{
  if (!live(W, MODE ? 2 : 1)) return;
  void* rnn_in = chunkp<MODE>(outb, 1);
  void* ax_out = chunkp<MODE>(outb, 2);

  const int tid = threadIdx.x;
  const int wave = tid>>6, lane = tid&63;
  const int lr = lane&15, lg = lane>>4;
  const u16* Wh = (const u16*)(W + O_HB);

  __shared__ __align__(16) u16 Et[8][1024];   // wave-private [16][64] bf16, slot-swizzled
  u16* myT = Et[wave];
  u32* myT32 = (u32*)myT;

#pragma unroll 1
  for (int p=0;p<2;p++){
    const void* src = p ? obs : ext;
    void* dst = p ? ax_out : rnn_in;
    const int h1 = p?HX1:HU1, h2 = p?HX2:HU2, h3 = p?HW3X:HW3U;
    const int b1o = p?O_PXB1:O_PUB1, b2o = p?O_PXB2:O_PUB2, b3o = p?O_AB1:O_RNB;

    // ---- weight fragments ----
    bf16x8 w1[4], w2[4][2], w3[4][2];
    float bb1[4], bb2[4], bb3[4];
#pragma unroll
    for (int n=0;n<4;n++){
      const int j = n*16 + lr;
      w1[n] = (lg<2) ? load16(Wh + h1 + j*16 + lg*8) : zfrag();
#pragma unroll
      for (int kk=0;kk<2;kk++){
        w2[n][kk] = load16(Wh + h2 + j*64 + kk*32 + lg*8);
        w3[n][kk] = load16(Wh + h3 + j*64 + kk*32 + lg*8);
      }
      bb1[n] = W[b1o+j]; bb2[n] = W[b2o+j]; bb3[n] = W[b3o+j];
    }

#pragma unroll 1
    for (int it=0; it<K1_NT; ++it){
      const size_t row0 = ((size_t)(blockIdx.x*8 + wave)*K1_NT + it)*16;

      // ---- input A-frag (K=16 padded to 32) ----
      bf16x8 xa;
      if (lg < 2){
        if constexpr (MODE){
          const float4* sp = (const float4*)((const float*)src + (row0+lr)*16);
          float4 f0 = sp[lg*2], f1 = sp[lg*2+1];
          union { short s[8]; bf16x8 v; } c;
          c.s[0]=(short)f2b(f0.x); c.s[1]=(short)f2b(f0.y);
          c.s[2]=(short)f2b(f0.z); c.s[3]=(short)f2b(f0.w);
          c.s[4]=(short)f2b(f1.x); c.s[5]=(short)f2b(f1.y);
          c.s[6]=(short)f2b(f1.z); c.s[7]=(short)f2b(f1.w);
          xa = c.v;
        } else {
          xa = load16((const u16*)src + (row0+lr)*16 + lg*8);
        }
      } else xa = zfrag();

      // ---- L1 ----
      f32x4 c[4];
#pragma unroll
      for (int n=0;n<4;n++){
        f32x4 ci = {bb1[n],bb1[n],bb1[n],bb1[n]};
        ci = mfma16(xa, w1[n], ci);
#pragma unroll
        for (int r=0;r<4;r++){
          float v = fmaxf(ci[r], 0.0f);
          const int b = lg*4 + r, j = n*16 + lr;
          myT[b*64 + (((j>>3)^(b&7))<<3) + (j&7)] = f2b(v);
        }
      }
      // ---- L2 ----
      {
        bf16x8 a0 = ldA64(myT32, lr, lg);
        bf16x8 a1 = ldA64(myT32, lr, 4+lg);
#pragma unroll
        for (int n=0;n<4;n++){
          f32x4 ci = {bb2[n],bb2[n],bb2[n],bb2[n]};
          ci = mfma16(a0, w2[n][0], ci);
          ci = mfma16(a1, w2[n][1], ci);
          c[n] = ci;
        }
#pragma unroll
        for (int n=0;n<4;n++)
#pragma unroll
          for (int r=0;r<4;r++){
            float v = fmaxf(c[n][r], 0.0f);
            const int b = lg*4 + r, j = n*16 + lr;
            myT[b*64 + (((j>>3)^(b&7))<<3) + (j&7)] = f2b(v);
          }
      }
      // ---- L3 (linear) ----
      {
        bf16x8 a0 = ldA64(myT32, lr, lg);
        bf16x8 a1 = ldA64(myT32, lr, 4+lg);
#pragma unroll
        for (int n=0;n<4;n++){
          f32x4 ci = {bb3[n],bb3[n],bb3[n],bb3[n]};
          ci = mfma16(a0, w3[n][0], ci);
          ci = mfma16(a1, w3[n][1], ci);
          c[n] = ci;
        }
#pragma unroll
        for (int n=0;n<4;n++)
#pragma unroll
          for (int r=0;r<4;r++){
            const int b = lg*4 + r, j = n*16 + lr;
            myT[b*64 + (((j>>3)^(b&7))<<3) + (j&7)] = f2b(c[n][r]);
          }
      }
      // ---- coalesced store: 2 slots per lane ----
#pragma unroll
      for (int s2=0;s2<2;s2++){
        const int s_lin = lane*2 + s2;
        const int r = s_lin>>3, sl = s_lin&7;
        uint4 v = ((const uint4*)myT32)[r*8 + (sl^(r&7))];
        if constexpr (MODE){
          float* dp = (float*)dst + (row0+r)*64 + sl*8;
          u32 w[4] = {v.x, v.y, v.z, v.w};
          float f[8];
#pragma unroll
          for (int i=0;i<4;i++){ f[2*i] = b2f((u16)(w[i]&0xffffu)); f[2*i+1] = b2f((u16)(w[i]>>16)); }
          ((float4*)dp)[0] = make_float4(f[0],f[1],f[2],f[3]);
          ((float4*)dp)[1] = make_float4(f[4],f[5],f[6],f[7]);
        } else {
          ((uint4*)((u16*)dst + (row0+r)*64))[sl] = v;
        }
      }
    }
  }
}

// 16-term partial dot with 2 accumulator chains
__device__ __forceinline__ float dot16(const float* w, float4 a, float4 b, float4 c, float4 d){
  float s0=0.f, s1=0.f;
  s0=fmaf(w[0],a.x,s0);  s1=fmaf(w[1],a.y,s1);  s0=fmaf(w[2],a.z,s0);  s1=fmaf(w[3],a.w,s1);
  s0=fmaf(w[4],b.x,s0);  s1=fmaf(w[5],b.y,s1);  s0=fmaf(w[6],b.z,s0);  s1=fmaf(w[7],b.w,s1);
  s0=fmaf(w[8],c.x,s0);  s1=fmaf(w[9],c.y,s1);  s0=fmaf(w[10],c.z,s0); s1=fmaf(w[11],c.w,s1);
  s0=fmaf(w[12],d.x,s0); s1=fmaf(w[13],d.y,s1); s0=fmaf(w[14],d.z,s0); s1=fmaf(w[15],d.w,s1);
  return s0+s1;
}

// -------------------- K2: sequential RNN + a-layer (WG per batch lane) --------------------
template<int MODE>
__global__ __launch_bounds__(256) void k2_rnn(
  const float* __restrict__ W, void* __restrict__ outb)
{
  if (!live(W, MODE ? 2 : 1)) return;
  void* a_seq  = chunkp<MODE>(outb, 0);
  void* rnn_in = chunkp<MODE>(outb, 1);
  void* ax     = chunkp<MODE>(outb, 2);
  void* d_seq  = chunkp<MODE>(outb, 3);

  const int b = blockIdx.x;
  const int tid = threadIdx.x;
  const int q = tid>>6, j = tid&63;

  float wh[16], wa1[16], wa2[16];
#pragma unroll
  for (int i=0;i<16;i++){
    wh[i]  = W[O_WHH + j*64  + q*16 + i];
    wa1[i] = W[O_AW1 + j*128 + q*16 + i];   // d-half (cols 0..63)
    wa2[i] = W[O_AW2 + j*64  + q*16 + i];
  }
  const float ab2j = W[O_AB2 + j];

  __shared__ __align__(16) float h_lds[64];
  __shared__ __align__(16) float v_lds[64];
  __shared__ __align__(16) float red1[256], red2[256], red3[256];
  if (tid < 64){ h_lds[tid] = 0.f; v_lds[tid] = 0.f; }
  __syncthreads();

  const size_t brow = (size_t)b*64 + j;
  for (int t=0; t<L+2; ++t){
    const float4* hv = (const float4*)(&h_lds[q*16]);
    const float4* vv = (const float4*)(&v_lds[q*16]);
    float4 h0=hv[0], h1=hv[1], h2=hv[2], h3=hv[3];
    float4 v0=vv[0], v1=vv[1], v2=vv[2], v3=vv[3];
    red1[tid] = dot16(wh,  h0,h1,h2,h3);
    red2[tid] = dot16(wa1, h0,h1,h2,h3);
    red3[tid] = dot16(wa2, v0,v1,v2,v3);
    __syncthreads();
    if (q==0){
      if (t < L){
        const size_t idx = (size_t)t*(BB*64) + brow;
        float s = red1[j]+red1[64+j]+red1[128+j]+red1[192+j] + ldOne<MODE>(rnn_in, idx);
        float hn = tanhf_fast(s);
        h_lds[j] = hn;
        stOne<MODE>(d_seq, idx, hn);
      }
    } else if (q==1){
      if (t>=1 && t<=L){
        const size_t idx = (size_t)(t-1)*(BB*64) + brow;
        float s = red2[j]+red2[64+j]+red2[128+j]+red2[192+j] + ldOne<MODE>(ax, idx);
        v_lds[j] = tanhf_fast(s);
      }
    } else if (q==2){
      if (t>=2){
        const size_t idx = (size_t)(t-2)*(BB*64) + brow;
        float s = red3[j]+red3[64+j]+red3[128+j]+red3[192+j] + ab2j;
        stOne<MODE>(a_seq, idx, s);
      }
    }
    __syncthreads();
  }
}

// -------------------- K4M: MFMA latent scan (WG per 16 batch lanes) --------------------
template<int MODE>
__global__ __launch_bounds__(512,2) void k4m(
  const float* __restrict__ W,
  const void* __restrict__ noise, void* __restrict__ outb)
{
  if (!live(W, MODE ? 2 : 1)) return;
  void* amu = chunkp<MODE>(outb, 0);   // reads a_seq, writes state_mu
  void* lsc = chunkp<MODE>(outb, 1);   // writes state_logsigma
  void* zc  = chunkp<MODE>(outb, 2);   // writes sampled_state
  void* dsq = chunkp<MODE>(outb, 3);   // reads d_seq

  const int G = blockIdx.x;
  const int tid = threadIdx.x;
  const int wave = tid>>6, lane = tid&63;
  const int lr = lane&15, lg = lane>>4;

  __shared__ __align__(16) u32 Zbuf[512];          // [16][64] bf16, 16B-slot swizzled
  __shared__ __align__(16) u32 Abuf[2][512];       // a_t   (same layout)
  __shared__ __align__(16) u32 Dbuf[2][512];       // d_t
  __shared__ __align__(16) u32 Ebuf[2][1024];      // eps as f32 bits, [16][64] plain
  __shared__ __align__(16) u32 Tpo[1024];          // t_po [16][128] bf16 swizzled
  __shared__ __align__(16) u32 Tpr[1024];
  __shared__ __align__(16) float Obuf[3*1024];     // po_mu/po_ls/pr_mu outs, [16][64] f32, slot-swizzled by b
  __shared__ float bmu[64], bls[64];

  const bool isPo = wave < 4;
  const int wq = wave & 3;
  const int jA = wq*32;

  // ---- stage-A weight fragments (all 8 waves) ----
  const int of1 = isPo ? O_POF1 : O_PRF1;
  const int of2 = isPo ? O_POF2 : O_PRF2;
  bf16x8 wf1[2][4], wf2[2][4];
  float bA1[2], bA2[2];
#pragma unroll
  for (int nt=0; nt<2; ++nt){
    const int j = jA + nt*16 + lr;
    bA1[nt] = W[(isPo?O_POF1B:O_PRF1B) + j];
    bA2[nt] = W[(isPo?O_POF2B:O_PRF2B) + j];
#pragma unroll
    for (int kk=0; kk<4; ++kk){
      const int k = kk*32 + lg*8;
      wf1[nt][kk] = wfrag(W, of1 + j*128 + k);
      wf2[nt][kk] = wfrag(W, of2 + j*128 + k);
    }
  }
  // ---- stage-B weight fragments (waves 0..5) ----
  const int mb = wave>>1, nh = wave&1;
  bf16x8 wb[2][4];
  if (wave < 6){
    const int ob = (mb==0) ? O_POMU : (mb==1 ? O_POLS : O_PRMU);
#pragma unroll
    for (int nt=0; nt<2; ++nt)
#pragma unroll
      for (int kk=0; kk<4; ++kk){
        const int j = nh*32 + nt*16 + lr;
        const int k = kk*32 + lg*8;
        wb[nt][kk] = wfrag(W, ob + j*128 + k);
      }
  }

  // ---- init: biases, zero z, initial prefetch ----
  if (tid < 64){ bmu[tid] = W[O_POMUB+tid] + W[O_PRMUB+tid]; bls[tid] = W[O_POLSB+tid]; }
  Zbuf[tid & 511] = 0;

  const int pr_ = lane>>2, pc = lane&3;      // prefetch row / col-group
  float4 pA[4], pE[4]; uint4 qA[2], qE[2];

  auto pf_issue = [&](int tt){
    const size_t rowb = ((size_t)tt*BB + G*16 + pr_)*64;
    const void* gsrc = (wave==6) ? amu : dsq;
    if constexpr (MODE){
      const float4* sp = (const float4*)((const float*)gsrc + rowb) + pc*4;
#pragma unroll
      for (int i=0;i<4;i++) pA[i] = sp[i];
      if (wave==6){
        const float4* ep = (const float4*)((const float*)noise + rowb) + pc*4;
#pragma unroll
        for (int i=0;i<4;i++) pE[i] = ep[i];
      }
    } else {
      const uint4* sp = (const uint4*)((const u16*)gsrc + rowb) + pc*2;
      qA[0] = sp[0]; qA[1] = sp[1];
      if (wave==6){
        const uint4* ep = (const uint4*)((const u16*)noise + rowb) + pc*2;
        qE[0] = ep[0]; qE[1] = ep[1];
      }
    }
  };
  auto pf_write = [&](int buf){
    u32* dst = (wave==6) ? Abuf[buf] : Dbuf[buf];
    uint4* d0 = (uint4*)dst + (pr_*8 + ((pc*2  ) ^ (pr_&7)));
    uint4* d1 = (uint4*)dst + (pr_*8 + ((pc*2+1) ^ (pr_&7)));
    if constexpr (MODE){
      u32 w[8];
#pragma unroll
      for (int i=0;i<4;i++){
        w[2*i]   = (u32)f2b(pA[i].x) | ((u32)f2b(pA[i].y)<<16);
        w[2*i+1] = (u32)f2b(pA[i].z) | ((u32)f2b(pA[i].w)<<16);
      }
      *d0 = make_uint4(w[0],w[1],w[2],w[3]);
      *d1 = make_uint4(w[4],w[5],w[6],w[7]);
      if (wave==6){
        uint4* eb = (uint4*)Ebuf[buf] + (pr_*16 + pc*4);
#pragma unroll
        for (int i=0;i<4;i++){
          union { float4 f; uint4 u; } cv; cv.f = pE[i];
          eb[i] = cv.u;
        }
      }
    } else {
      *d0 = qA[0]; *d1 = qA[1];
      if (wave==6){
        u32* Eb = Ebuf[buf] + pr_*64 + pc*16;
        u32 ww[4] = {qE[0].x, qE[0].y, qE[0].z, qE[0].w};
#pragma unroll
        for (int i=0;i<4;i++){ Eb[2*i] = ww[i]<<16; Eb[2*i+1] = ww[i] & 0xffff0000u; }
        u32 w2[4] = {qE[1].x, qE[1].y, qE[1].z, qE[1].w};
#pragma unroll
        for (int i=0;i<4;i++){ Eb[8+2*i] = w2[i]<<16; Eb[8+2*i+1] = w2[i] & 0xffff0000u; }
      }
    }
  };

  if (wave >= 6){ pf_issue(0); pf_write(0); }
  __syncthreads();

  for (int t=0; t<L; ++t){
    const int cur = t&1, nb = cur^1;
    if (wave >= 6 && t+1 < L) pf_issue(t+1);   // issue early; written after S2

    // ---- stage A: all 8 waves, 16 MFMA each ----
    const u32* ADc = isPo ? Abuf[cur] : Dbuf[cur];
    bf16x8 a0 = ldA64(Zbuf, lr, lg);
    bf16x8 a1 = ldA64(Zbuf, lr, 4+lg);
    bf16x8 a2 = ldA64(ADc,  lr, lg);
    bf16x8 a3 = ldA64(ADc,  lr, 4+lg);
    f32x4 c1[2], c2[2];
#pragma unroll
    for (int nt=0; nt<2; ++nt){
      f32x4 i1 = {bA1[nt],bA1[nt],bA1[nt],bA1[nt]};
      f32x4 i2 = {bA2[nt],bA2[nt],bA2[nt],bA2[nt]};
      i1 = mfma16(a0, wf1[nt][0], i1);
      i1 = mfma16(a1, wf1[nt][1], i1);
      i1 = mfma16(a2, wf1[nt][2], i1);
      i1 = mfma16(a3, wf1[nt][3], i1);
      i2 = mfma16(a0, wf2[nt][0], i2);
      i2 = mfma16(a1, wf2[nt][1], i2);
      i2 = mfma16(a2, wf2[nt][2], i2);
      i2 = mfma16(a3, wf2[nt][3], i2);
      c1[nt] = i1; c2[nt] = i2;
    }
    // t = tanh(fc1)*sigm(fc2), write bf16 into T (A-operand layout, swizzled)
    u16* Td = (u16*)(isPo ? Tpo : Tpr);
#pragma unroll
    for (int nt=0; nt<2; ++nt)
#pragma unroll
      for (int r=0; r<4; ++r){
        float tv = tanhf_fast(c1[nt][r]) * sigm_fast(c2[nt][r]);
        const int j = jA + nt*16 + lr;
        const int b = lg*4 + r;
        Td[b*128 + (((j>>3)^(b&7))<<3) + (j&7)] = f2b(tv);
      }
    __syncthreads();  // S2: T ready

    // ---- stage B: waves 0..5 output matmuls; waves 6,7 write prefetched ----
    if (wave < 6){
      const u32* Ts = (mb==2) ? Tpr : Tpo;
      bf16x8 t0 = ldT(Ts, lr, lg);
      bf16x8 t1 = ldT(Ts, lr, 4+lg);
      bf16x8 t2 = ldT(Ts, lr, 8+lg);
      bf16x8 t3 = ldT(Ts, lr, 12+lg);
      f32x4 d0 = {0.f,0.f,0.f,0.f}, d1 = {0.f,0.f,0.f,0.f};
      d0 = mfma16(t0, wb[0][0], d0);
      d0 = mfma16(t1, wb[0][1], d0);
      d0 = mfma16(t2, wb[0][2], d0);
      d0 = mfma16(t3, wb[0][3], d0);
      d1 = mfma16(t0, wb[1][0], d1);
      d1 = mfma16(t1, wb[1][1], d1);
      d1 = mfma16(t2, wb[1][2], d1);
      d1 = mfma16(t3, wb[1][3], d1);
      float* Od = &Obuf[mb*1024];
#pragma unroll
      for (int r=0; r<4; ++r){
        const int b = lg*4 + r;
        const int j0 = nh*32 + lr;
        const int j1 = nh*32 + 16 + lr;
        Od[b*64 + (((j0>>2)^(b&7))<<2) + (j0&3)] = d0[r];
        Od[b*64 + (((j1>>2)^(b&7))<<2) + (j1&3)] = d1[r];
      }
    } else if (t+1 < L){
      pf_write(nb);
    }
    __syncthreads();  // S3: outs + next a/d/eps ready

    // ---- z update: 512 threads cover 16x64, 2 outputs each ----
    {
      const int b = tid>>5;
      const int j = (tid&31)*2;
      const int sidx = b*64 + (((j>>2)^(b&7))<<2) + (j&3);
      float2 vpo = *(const float2*)&Obuf[0*1024 + sidx];
      float2 vls = *(const float2*)&Obuf[1*1024 + sidx];
      float2 vpr = *(const float2*)&Obuf[2*1024 + sidx];
      float2 bm = *(const float2*)&bmu[j];
      float2 bl = *(const float2*)&bls[j];
      float e0 = __uint_as_float(Ebuf[cur][b*64 + j]);
      float e1 = __uint_as_float(Ebuf[cur][b*64 + j + 1]);
      float mu0 = vpo.x + vpr.x + bm.x;
      float mu1 = vpo.y + vpr.y + bm.y;
      float ls0 = vls.x + bl.x;
      float ls1 = vls.y + bl.y;
      float z0 = fmaf(EXP2(ls0*0.7213475204444817f), e0, mu0);
      float z1 = fmaf(EXP2(ls1*0.7213475204444817f), e1, mu1);
      // write z into Zbuf (bf16 pair, swizzled slot)
      Zbuf[b*32 + (((j>>3)^(b&7))<<2) + ((j&7)>>1)] = (u32)f2b(z0) | ((u32)f2b(z1)<<16);
      // global outputs
      const size_t idx = ((size_t)t*BB + G*16 + b)*64 + j;
      if constexpr (MODE){
        *(float2*)((float*)amu + idx) = make_float2(mu0, mu1);
        *(float2*)((float*)lsc + idx) = make_float2(ls0, ls1);
        *(float2*)((float*)zc  + idx) = make_float2(z0, z1);
      } else {
        *(u32*)((u16*)amu + idx) = (u32)f2b(mu0) | ((u32)f2b(mu1)<<16);
        *(u32*)((u16*)lsc + idx) = (u32)f2b(ls0) | ((u32)f2b(ls1)<<16);
        *(u32*)((u16*)zc  + idx) = (u32)f2b(z0)  | ((u32)f2b(z1)<<16);
      }
    }
    __syncthreads();  // S4: z ready for next step
  }
}

extern "C" void kernel_launch(void* const* d_in, const int* in_sizes, int n_in,
                              void* d_out, int out_size, void* d_ws, size_t ws_size,
                              hipStream_t stream)
{
  (void)in_sizes; (void)n_in; (void)out_size; (void)ws_size;

  const void* ext   = d_in[0];
  const void* obs   = d_in[1];
  const void* noise = d_in[2];
  float* W = (float*)d_ws;

  kprobe<<<1,64,0,stream>>>((const u32*)ext, (u32*)W + O_FLAG);

#define K0ARGS \
    d_in[3],  d_in[4],  d_in[5],  d_in[6],  d_in[7],  d_in[8],  d_in[9],  d_in[10], \
    d_in[11], d_in[12], d_in[13], d_in[14], d_in[15], d_in[16], d_in[17], d_in[18], \
    d_in[19], d_in[20], d_in[21], d_in[22], d_in[23], d_in[24], d_in[25], d_in[26], \
    d_in[27], d_in[28], d_in[29], d_in[30], d_in[31], d_in[32], W

  k0_convert<0><<<64,256,0,stream>>>(K0ARGS);
  k0_convert<1><<<64,256,0,stream>>>(K0ARGS);
#undef K0ARGS

  k1m<0><<<NROWS/(8*K1_NT*16), 512, 0, stream>>>(ext, obs, W, d_out);
  k1m<1><<<NROWS/(8*K1_NT*16), 512, 0, stream>>>(ext, obs, W, d_out);

  k2_rnn<0><<<BB, 256, 0, stream>>>(W, d_out);
  k2_rnn<1><<<BB, 256, 0, stream>>>(W, d_out);

  k4m<0><<<32, 512, 0, stream>>>(W, noise, d_out);
  k4m<1><<<32, 512, 0, stream>>>(W, noise, d_out);
}